// Round 12
// baseline (211.997 us; speedup 1.0000x reference)
//
#include <hip/hip_runtime.h>
#include <hip/hip_bf16.h>

// Problem constants
#define NB    4
#define NP    12          // P1 == P == 12
#define NN_   207
#define DM    128         // d_model
#define DHID  256
#define M_TOK 9936        // NB*NP*NN_
#define MPH   9984        // padded rows (78*128)

typedef float        f32x4 __attribute__((ext_vector_type(4)));
typedef unsigned int u32x4 __attribute__((ext_vector_type(4)));
typedef __bf16       bf16x8 __attribute__((ext_vector_type(8)));

static __device__ __forceinline__ unsigned int pk_bf2(float a, float b) {
    __hip_bfloat16 ba = __float2bfloat16(a);
    __hip_bfloat16 bb = __float2bfloat16(b);
    unsigned short ua = *reinterpret_cast<unsigned short*>(&ba);
    unsigned short ub = *reinterpret_cast<unsigned short*>(&bb);
    return (unsigned int)ua | ((unsigned int)ub << 16);
}

// ---------------- prep: W2->bf16 | meta-MFMA (h->bf16, Qb) ----------------
// (unchanged from round 10/11 — verified)
__global__ __launch_bounds__(256) void k_prep(const float* __restrict__ W2,
                                              unsigned short* __restrict__ W2b,
                                              const float* __restrict__ x,
                                              const float* __restrict__ ct,
                                              const float* __restrict__ W1,
                                              const float* __restrict__ b1,
                                              const float* __restrict__ b2,
                                              unsigned short* __restrict__ hbf,
                                              float* __restrict__ Qb) {
    const int t = threadIdx.x;
    const int bid = blockIdx.x;
    if (bid < 2048) {
        int i = bid * 256 + t;
        const f32x4* in = reinterpret_cast<const f32x4*>(W2);
        f32x4 v0 = in[2 * i], v1 = in[2 * i + 1];
        u32x4 o;
        o[0] = pk_bf2(v0[0], v0[1]);
        o[1] = pk_bf2(v0[2], v0[3]);
        o[2] = pk_bf2(v1[0], v1[1]);
        o[3] = pk_bf2(v1[2], v1[3]);
        reinterpret_cast<u32x4*>(W2b)[i] = o;
        return;
    }
    __shared__ unsigned short AB[128 * 128];   // 32KB: ct_bf then x_bf, swizzled
    __shared__ unsigned short WB[64 * 128];    // 16KB: W1b / b2b chunk, swizzled
    const int m0 = (bid - 2048) * 128;
    const int w = t >> 6, l = t & 63;
    const int lr = l & 15, g = l >> 4;

    #pragma unroll
    for (int it = 0; it < 8; ++it) {
        int r = (t >> 4) + it * 16;
        int gg = t & 15;
        int m = m0 + r;
        f32x4 a = (f32x4)(0.0f), b = (f32x4)(0.0f);
        if (m < M_TOK) {
            a = *reinterpret_cast<const f32x4*>(&ct[(size_t)m * DM + gg * 8]);
            b = *reinterpret_cast<const f32x4*>(&ct[(size_t)m * DM + gg * 8 + 4]);
        }
        u32x4 pk;
        pk[0] = pk_bf2(a[0], a[1]); pk[1] = pk_bf2(a[2], a[3]);
        pk[2] = pk_bf2(b[0], b[1]); pk[3] = pk_bf2(b[2], b[3]);
        *reinterpret_cast<u32x4*>(&AB[r * 128 + ((gg ^ (r & 7)) * 8)]) = pk;
    }

    for (int jc = 0; jc < 4; ++jc) {
        __syncthreads();
        #pragma unroll
        for (int it = 0; it < 4; ++it) {
            int r = (t >> 4) + it * 16;
            int gg = t & 15;
            const float* src = &W1[(size_t)(jc * 64 + r) * DM + gg * 8];
            f32x4 a = *reinterpret_cast<const f32x4*>(src);
            f32x4 b = *reinterpret_cast<const f32x4*>(src + 4);
            u32x4 pk;
            pk[0] = pk_bf2(a[0], a[1]); pk[1] = pk_bf2(a[2], a[3]);
            pk[2] = pk_bf2(b[0], b[1]); pk[3] = pk_bf2(b[2], b[3]);
            *reinterpret_cast<u32x4*>(&WB[r * 128 + ((gg ^ (r & 7)) * 8)]) = pk;
        }
        __syncthreads();
        f32x4 acc[2][4];
        #pragma unroll
        for (int a2 = 0; a2 < 2; ++a2)
            #pragma unroll
            for (int jf = 0; jf < 4; ++jf) acc[a2][jf] = (f32x4)(0.0f);
        #pragma unroll
        for (int ks = 0; ks < 4; ++ks) {
            bf16x8 A2[2], B4[4];
            #pragma unroll
            for (int tf = 0; tf < 2; ++tf) {
                int row = (2 * w + tf) * 16 + lr;
                A2[tf] = *reinterpret_cast<const bf16x8*>(
                    &AB[row * 128 + (((ks * 4 + g) ^ (row & 7)) * 8)]);
            }
            #pragma unroll
            for (int jf = 0; jf < 4; ++jf) {
                int row = jf * 16 + lr;
                B4[jf] = *reinterpret_cast<const bf16x8*>(
                    &WB[row * 128 + (((ks * 4 + g) ^ (row & 7)) * 8)]);
            }
            #pragma unroll
            for (int tf = 0; tf < 2; ++tf)
                #pragma unroll
                for (int jf = 0; jf < 4; ++jf)
                    acc[tf][jf] = __builtin_amdgcn_mfma_f32_16x16x32_bf16(
                        A2[tf], B4[jf], acc[tf][jf], 0, 0, 0);
        }
        #pragma unroll
        for (int jf = 0; jf < 4; ++jf) {
            int j = jc * 64 + jf * 16 + lr;
            float bv = b1[j];
            #pragma unroll
            for (int tf = 0; tf < 2; ++tf)
                #pragma unroll
                for (int rr = 0; rr < 4; ++rr) {
                    int m = m0 + (2 * w + tf) * 16 + g * 4 + rr;
                    if (m < M_TOK) {
                        float hv = fmaxf(acc[tf][jf][rr] + bv, 0.0f);
                        __hip_bfloat16 hb = __float2bfloat16(hv);
                        hbf[(size_t)m * DHID + j] = *reinterpret_cast<unsigned short*>(&hb);
                    }
                }
        }
    }

    __syncthreads();
    #pragma unroll
    for (int it = 0; it < 8; ++it) {
        int r = (t >> 4) + it * 16;
        int gg = t & 15;
        int m = m0 + r;
        f32x4 a = (f32x4)(0.0f), b = (f32x4)(0.0f);
        if (m < M_TOK) {
            a = *reinterpret_cast<const f32x4*>(&x[(size_t)m * DM + gg * 8]);
            b = *reinterpret_cast<const f32x4*>(&x[(size_t)m * DM + gg * 8 + 4]);
        }
        u32x4 pk;
        pk[0] = pk_bf2(a[0], a[1]); pk[1] = pk_bf2(a[2], a[3]);
        pk[2] = pk_bf2(b[0], b[1]); pk[3] = pk_bf2(b[2], b[3]);
        *reinterpret_cast<u32x4*>(&AB[r * 128 + ((gg ^ (r & 7)) * 8)]) = pk;
    }
    for (int oc = 0; oc < 2; ++oc) {
        #pragma unroll
        for (int it = 0; it < 4; ++it) {
            int r = (t >> 4) + it * 16;
            int gg = t & 15;
            const float* src = &b2[(size_t)(oc * 64 + r) * DM + gg * 8];
            f32x4 a = *reinterpret_cast<const f32x4*>(src);
            f32x4 b = *reinterpret_cast<const f32x4*>(src + 4);
            u32x4 pk;
            pk[0] = pk_bf2(a[0], a[1]); pk[1] = pk_bf2(a[2], a[3]);
            pk[2] = pk_bf2(b[0], b[1]); pk[3] = pk_bf2(b[2], b[3]);
            *reinterpret_cast<u32x4*>(&WB[r * 128 + ((gg ^ (r & 7)) * 8)]) = pk;
        }
        __syncthreads();
        f32x4 acc[2][4];
        #pragma unroll
        for (int a2 = 0; a2 < 2; ++a2)
            #pragma unroll
            for (int of = 0; of < 4; ++of) acc[a2][of] = (f32x4)(0.0f);
        #pragma unroll
        for (int ks = 0; ks < 4; ++ks) {
            bf16x8 A2[2], B4[4];
            #pragma unroll
            for (int tf = 0; tf < 2; ++tf) {
                int row = (2 * w + tf) * 16 + lr;
                A2[tf] = *reinterpret_cast<const bf16x8*>(
                    &AB[row * 128 + (((ks * 4 + g) ^ (row & 7)) * 8)]);
            }
            #pragma unroll
            for (int of = 0; of < 4; ++of) {
                int row = of * 16 + lr;
                B4[of] = *reinterpret_cast<const bf16x8*>(
                    &WB[row * 128 + (((ks * 4 + g) ^ (row & 7)) * 8)]);
            }
            #pragma unroll
            for (int tf = 0; tf < 2; ++tf)
                #pragma unroll
                for (int of = 0; of < 4; ++of)
                    acc[tf][of] = __builtin_amdgcn_mfma_f32_16x16x32_bf16(
                        A2[tf], B4[of], acc[tf][of], 0, 0, 0);
        }
        #pragma unroll
        for (int of = 0; of < 4; ++of) {
            int o = oc * 64 + of * 16 + lr;
            #pragma unroll
            for (int tf = 0; tf < 2; ++tf)
                #pragma unroll
                for (int rr = 0; rr < 4; ++rr) {
                    int m = m0 + (2 * w + tf) * 16 + g * 4 + rr;
                    if (m < M_TOK) Qb[(size_t)m * DM + o] = acc[tf][of][rr];
                }
        }
        __syncthreads();
    }
}

// ---------------- G-form GEMM v3: counted-vmcnt pipeline (T3+T4) ----------------
// Same geometry as r11 (256od x 128m, BK=32, 8 steps, 2x2 waves, 32 MFMA/wave/step)
// but: global_load_lds staging (no reg round-trip), 3 LDS buffers, depth-2 prefetch,
// ONE barrier/step with s_waitcnt vmcnt(6) (never 0 until tail) — loads span barriers.
// Swizzle via pre-swizzled per-lane GLOBAL source + same XOR on read (rule #21);
// LDS content mapping identical to r11's verified layout.
__global__ __launch_bounds__(256, 2) void k_gemm(const unsigned short* __restrict__ W2b,
                                                 const unsigned short* __restrict__ hbf,
                                                 const float* __restrict__ xin,
                                                 float* __restrict__ QpT) {
    __shared__ unsigned short As[3][8192];   // 16KB per buffer
    __shared__ unsigned short Bs[3][4096];   //  8KB per buffer
    const int t = threadIdx.x;
    const int ob2 = blockIdx.x & 63;
    const int mb  = blockIdx.x >> 6;         // 0..77
    const int od0 = ob2 * 256;
    const int m0  = mb * 128;
    const int w = t >> 6, l = t & 63;
    const int wo = w >> 1, wm = w & 1;
    const int lr = l & 15, g = l >> 4;

    // per-lane pre-swizzled global source: lane covers LDS slot (row=base+(l>>2), pos=l&3);
    // source chunk = pos ^ ((row>>1)&3) = (l&3) ^ ((l>>3)&3)   [base rows are mult of 16]
    const int lchunk = ((l & 3) ^ ((l >> 3) & 3)) * 8;          // shorts
    const unsigned short* aSrc = W2b + (size_t)(od0 + w * 64 + (l >> 2)) * 256 + lchunk;
    const unsigned short* bSrc = hbf + (size_t)(m0 + w * 32 + (l >> 2)) * 256 + lchunk;

#define GL(SRC, DST) __builtin_amdgcn_global_load_lds( \
        (const __attribute__((address_space(1))) unsigned int*)(SRC), \
        (__attribute__((address_space(3))) unsigned int*)(DST), 16, 0, 0)
    // A: wave w stages rows [w*64, w*64+64) in 4 calls of 16 rows; B: [w*32,+32) in 2 calls
#define STAGE(BUF, K) do { \
        GL(aSrc + (K) * 32,         &As[BUF][w * 2048]); \
        GL(aSrc + (K) * 32 + 4096,  &As[BUF][w * 2048 + 512]); \
        GL(aSrc + (K) * 32 + 8192,  &As[BUF][w * 2048 + 1024]); \
        GL(aSrc + (K) * 32 + 12288, &As[BUF][w * 2048 + 1536]); \
        GL(bSrc + (K) * 32,         &Bs[BUF][w * 1024]); \
        GL(bSrc + (K) * 32 + 4096,  &Bs[BUF][w * 1024 + 512]); \
    } while (0)

    // read offsets: row = (wo*128|wm*64) + f*16 + lr; chunk pos = g ^ ((lr>>1)&3)
    const int rswz = (g ^ ((lr >> 1) & 3)) * 8;
    const int aR = wo * 4096 + lr * 32 + rswz;   // + fo*512
    const int bR = wm * 2048 + lr * 32 + rswz;   // + fm*512

    f32x4 acc[8][4];
    #pragma unroll
    for (int fo = 0; fo < 8; ++fo)
        #pragma unroll
        for (int fm = 0; fm < 4; ++fm) acc[fo][fm] = (f32x4)(0.0f);

    // prologue: tiles 0 and 1 in flight; wait only for tile 0 (6 newest stay outstanding)
    STAGE(0, 0);
    STAGE(1, 1);
    asm volatile("s_waitcnt vmcnt(6)" ::: "memory");
    __builtin_amdgcn_s_barrier();

    #pragma unroll
    for (int s = 0; s < 8; ++s) {
        const int cur = s % 3;
        if (s < 6) STAGE((s + 2) % 3, s + 2);   // issue tile s+2 (buffer free since end of s-1)
        bf16x8 bf0 = *reinterpret_cast<const bf16x8*>(&Bs[cur][bR]);
        bf16x8 bf1 = *reinterpret_cast<const bf16x8*>(&Bs[cur][bR + 512]);
        bf16x8 bf2 = *reinterpret_cast<const bf16x8*>(&Bs[cur][bR + 1024]);
        bf16x8 bf3 = *reinterpret_cast<const bf16x8*>(&Bs[cur][bR + 1536]);
        __builtin_amdgcn_s_setprio(1);
        #pragma unroll
        for (int fo = 0; fo < 8; ++fo) {
            bf16x8 af = *reinterpret_cast<const bf16x8*>(&As[cur][aR + fo * 512]);
            acc[fo][0] = __builtin_amdgcn_mfma_f32_16x16x32_bf16(af, bf0, acc[fo][0], 0, 0, 0);
            acc[fo][1] = __builtin_amdgcn_mfma_f32_16x16x32_bf16(af, bf1, acc[fo][1], 0, 0, 0);
            acc[fo][2] = __builtin_amdgcn_mfma_f32_16x16x32_bf16(af, bf2, acc[fo][2], 0, 0, 0);
            acc[fo][3] = __builtin_amdgcn_mfma_f32_16x16x32_bf16(af, bf3, acc[fo][3], 0, 0, 0);
        }
        __builtin_amdgcn_s_setprio(0);
        // counted wait: tile s+1 landed; the 6 loads just issued (tile s+2) stay in flight
        if (s < 6)       asm volatile("s_waitcnt vmcnt(6)" ::: "memory");
        else if (s == 6) asm volatile("s_waitcnt vmcnt(0)" ::: "memory");
        if (s < 7) __builtin_amdgcn_s_barrier();
    }
#undef STAGE
#undef GL

    // epilogue: acc[fo][fm][r] = G[od0 + wo*128 + fo*16 + g*4 + r][m0 + wm*64 + fm*16 + lr]
    const int o = ob2 * 2 + wo;
    #pragma unroll
    for (int fm = 0; fm < 4; ++fm) {
        int m = m0 + wm * 64 + fm * 16 + lr;
        int mx = m < M_TOK ? m : (M_TOK - 1);
        const f32x4* xr = reinterpret_cast<const f32x4*>(&xin[(size_t)mx * DM]);
        float q = 0.0f;
        #pragma unroll
        for (int fo = 0; fo < 8; ++fo) {
            f32x4 xv = xr[fo * 4 + g];
            q += xv[0] * acc[fo][fm][0] + xv[1] * acc[fo][fm][1]
               + xv[2] * acc[fo][fm][2] + xv[3] * acc[fo][fm][3];
        }
        q += __shfl_xor(q, 16, 64);
        q += __shfl_xor(q, 32, 64);
        if (l < 16 && m < M_TOK) QpT[(size_t)o * MPH + m] = q;
    }
}

// ---------------- attention + W_out(global-stream) + residual + layernorm ----------------
// (unchanged from round 10/11 — verified)
__global__ __launch_bounds__(256) void k_attn(const float* __restrict__ QpT,
                                              const float* __restrict__ Qb,
                                              const float* __restrict__ Kenc,
                                              const float* __restrict__ Venc,
                                              const float* __restrict__ xin,
                                              const float* __restrict__ Wout,
                                              const float* __restrict__ gamma,
                                              const float* __restrict__ beta,
                                              float* __restrict__ out) {
    __shared__ float Qs[12][132];
    __shared__ float Ks[12][132];
    __shared__ float Vs[12][132];
    __shared__ float Ss[12][12][8];
    __shared__ float Os[12][132];
    const int t = threadIdx.x;
    const int b = blockIdx.x / NN_;
    const int n = blockIdx.x % NN_;

    for (int e = t; e < 1536; e += 256) {
        int row = e >> 7, o = e & 127;
        size_t mrow = (size_t)(b * NP + row) * NN_ + n;
        Qs[row][o] = Qb[mrow * DM + o] + QpT[(size_t)o * MPH + mrow];
    }
    for (int e = t; e < 384; e += 256) {
        int row = e >> 5, c4 = e & 31;
        size_t mrow = (size_t)(b * NP + row) * NN_ + n;
        *reinterpret_cast<f32x4*>(&Ks[row][c4 * 4]) =
            *reinterpret_cast<const f32x4*>(&Kenc[mrow * DM + c4 * 4]);
        *reinterpret_cast<f32x4*>(&Vs[row][c4 * 4]) =
            *reinterpret_cast<const f32x4*>(&Venc[mrow * DM + c4 * 4]);
    }
    __syncthreads();
    if (t < 144) {
        int q = t / 12, p = t % 12;
        #pragma unroll
        for (int hh = 0; hh < 8; ++hh) {
            const f32x4* qv = reinterpret_cast<const f32x4*>(&Qs[q][hh * 16]);
            const f32x4* kv = reinterpret_cast<const f32x4*>(&Ks[p][hh * 16]);
            float s = 0.0f;
            #pragma unroll
            for (int c = 0; c < 4; ++c) {
                f32x4 a = qv[c], bb = kv[c];
                s += a[0] * bb[0] + a[1] * bb[1] + a[2] * bb[2] + a[3] * bb[3];
            }
            Ss[q][p][hh] = s * 0.25f;
        }
    }
    __syncthreads();
    if (t < 96) {
        int q = t >> 3, hh = t & 7;
        float mx = -1e30f;
        #pragma unroll
        for (int p = 0; p < 12; ++p) mx = fmaxf(mx, Ss[q][p][hh]);
        float ev[12]; float sum = 0.0f;
        #pragma unroll
        for (int p = 0; p < 12; ++p) { ev[p] = __expf(Ss[q][p][hh] - mx); sum += ev[p]; }
        float inv = 1.0f / sum;
        #pragma unroll
        for (int p = 0; p < 12; ++p) Ss[q][p][hh] = ev[p] * inv;
    }
    __syncthreads();
    #pragma unroll
    for (int i = 0; i < 6; ++i) {
        int e = i * 256 + t;
        int q = e >> 7, hk = e & 127, hh = hk >> 4;
        float acc = 0.0f;
        #pragma unroll
        for (int p = 0; p < 12; ++p) acc += Ss[q][p][hh] * Vs[p][hk];
        Os[q][hk] = acc;
    }
    __syncthreads();
    {
        const int o  = t & 127;
        const int qh = (t >> 7) * 6;
        const f32x4* wrow = reinterpret_cast<const f32x4*>(&Wout[(size_t)o * DM]);
        float pacc[6] = {0, 0, 0, 0, 0, 0};
        for (int c = 0; c < 32; ++c) {
            f32x4 wv = wrow[c];
            #pragma unroll
            for (int qq = 0; qq < 6; ++qq) {
                f32x4 ov = *reinterpret_cast<const f32x4*>(&Os[qh + qq][c * 4]);
                pacc[qq] += wv[0] * ov[0] + wv[1] * ov[1] + wv[2] * ov[2] + wv[3] * ov[3];
            }
        }
        #pragma unroll
        for (int qq = 0; qq < 6; ++qq) {
            size_t mrow = (size_t)(b * NP + qh + qq) * NN_ + n;
            Qs[qh + qq][o] = pacc[qq] + xin[mrow * DM + o];
        }
    }
    __syncthreads();
    const int wv_ = t >> 6, ll = t & 63;
    for (int rq = wv_; rq < 12; rq += 4) {
        float v0 = Qs[rq][ll], v1 = Qs[rq][ll + 64];
        float s = v0 + v1, ss = v0 * v0 + v1 * v1;
        #pragma unroll
        for (int msk = 1; msk < 64; msk <<= 1) {
            s += __shfl_xor(s, msk, 64);
            ss += __shfl_xor(ss, msk, 64);
        }
        float mu = s * (1.0f / 128.0f);
        float var = ss * (1.0f / 128.0f) - mu * mu;
        float rs = rsqrtf(var + 1e-5f);
        size_t mrow = (size_t)(b * NP + rq) * NN_ + n;
        out[mrow * DM + ll]      = (v0 - mu) * rs * gamma[ll] + beta[ll];
        out[mrow * DM + ll + 64] = (v1 - mu) * rs * gamma[ll + 64] + beta[ll + 64];
    }
}

// ---------------- launcher ----------------
extern "C" void kernel_launch(void* const* d_in, const int* in_sizes, int n_in,
                              void* d_out, int out_size, void* d_ws, size_t ws_size,
                              hipStream_t stream) {
    const float* xin   = (const float*)d_in[0];
    const float* Kenc  = (const float*)d_in[1];
    const float* Venc  = (const float*)d_in[2];
    const float* ct    = (const float*)d_in[3];
    const float* W1    = (const float*)d_in[4];
    const float* b1    = (const float*)d_in[5];
    const float* W2    = (const float*)d_in[6];
    const float* b2    = (const float*)d_in[7];
    const float* Wout  = (const float*)d_in[8];
    const float* gamma = (const float*)d_in[9];
    const float* beta  = (const float*)d_in[10];
    float* out = (float*)d_out;

    char* ws = (char*)d_ws;
    unsigned short* W2b = (unsigned short*)(ws);              //  8,388,608 B  [16384][256] bf16
    unsigned short* hbf = (unsigned short*)(ws + 8388608);    //  5,111,808 B  [9984][256] bf16
    float* Qb  = (float*)(ws + 13500416);                     //  5,087,232 B  [9936][128] f32
    float* QpT = (float*)(ws + 18587648);                     //  5,111,808 B  [128][9984] f32

    // zero the hbf pad rows (9936..9983) so the GEMM's B-tail is clean
    hipMemsetAsync(ws + 8388608 + (size_t)M_TOK * DHID * 2, 0,
                   (size_t)(MPH - M_TOK) * DHID * 2, stream);
    hipLaunchKernelGGL(k_prep, dim3(2126), dim3(256), 0, stream,
                       W2, W2b, xin, ct, W1, b1, b2, hbf, Qb);
    hipLaunchKernelGGL(k_gemm, dim3(78 * 64), dim3(256), 0, stream, W2b, hbf, xin, QpT);
    hipLaunchKernelGGL(k_attn, dim3(828), dim3(256), 0, stream, QpT, Qb, Kenc, Venc,
                       xin, Wout, gamma, beta, out);
}

// Round 13
// 178.201 us; speedup vs baseline: 1.1897x; 1.1897x over previous
//
#include <hip/hip_runtime.h>
#include <hip/hip_bf16.h>

// Problem constants
#define NB    4
#define NP    12          // P1 == P == 12
#define NN_   207
#define DM    128         // d_model
#define DHID  256
#define M_TOK 9936        // NB*NP*NN_
#define M_PAD 9984        // padded to 156*64 (xT / hb / Qp row space)
#define KSPLIT 8          // j-splits (j-chunk = 32)

typedef float        f32x4 __attribute__((ext_vector_type(4)));
typedef unsigned int u32x4 __attribute__((ext_vector_type(4)));
typedef __bf16       bf16x8 __attribute__((ext_vector_type(8)));

static __device__ __forceinline__ unsigned int pk_bf2(float a, float b) {
    __hip_bfloat16 ba = __float2bfloat16(a);
    __hip_bfloat16 bb = __float2bfloat16(b);
    unsigned short ua = *reinterpret_cast<unsigned short*>(&ba);
    unsigned short ub = *reinterpret_cast<unsigned short*>(&bb);
    return (unsigned int)ua | ((unsigned int)ub << 16);
}
// hardware packed f32->bf16 (RNE), 1 instr per 2 elements (no builtin on gfx950).
// src0 -> low 16, src1 -> high 16 (same layout as pk_bf2).
static __device__ __forceinline__ unsigned int cvt_pk_bf16(float lo, float hi) {
    unsigned int r;
    asm("v_cvt_pk_bf16_f32 %0, %1, %2" : "=v"(r) : "v"(lo), "v"(hi));
    return r;
}

// ---------------- prep: W2->bf16 | transpose x->xT | meta-MFMA (h f32, Qb) ----------
// blocks [0,2048): cvt_w2; [2048,3296): transpose (r1-verified);
// [3296,3374): meta via bf16 MFMA (r10-verified), h written as f32 for the gemm stage.
__global__ __launch_bounds__(256) void k_prep(const float* __restrict__ W2,
                                              unsigned short* __restrict__ W2b,
                                              const float* __restrict__ x,
                                              float* __restrict__ xT,
                                              const float* __restrict__ ct,
                                              const float* __restrict__ W1,
                                              const float* __restrict__ b1,
                                              const float* __restrict__ b2,
                                              float* __restrict__ hb,
                                              float* __restrict__ Qb) {
    const int t = threadIdx.x;
    const int bid = blockIdx.x;
    if (bid < 2048) {
        // ---- W2 fp32 -> bf16, 8 f32 per thread ----
        int i = bid * 256 + t;
        const f32x4* in = reinterpret_cast<const f32x4*>(W2);
        f32x4 v0 = in[2 * i], v1 = in[2 * i + 1];
        u32x4 o;
        o[0] = pk_bf2(v0[0], v0[1]);
        o[1] = pk_bf2(v0[2], v0[3]);
        o[2] = pk_bf2(v1[0], v1[1]);
        o[3] = pk_bf2(v1[2], v1[3]);
        reinterpret_cast<u32x4*>(W2b)[i] = o;
        return;
    }
    if (bid < 3296) {
        // ---- transpose inputs -> xT[128][M_PAD], pad m>=M_TOK with 0 ----
        __shared__ float tile[32][33];
        const int b = bid - 2048;
        const int bm = b >> 2;          // 312 m-tiles of 32
        const int bd = b & 3;           // 4 d-tiles of 32
        const int m0 = bm * 32, d0 = bd * 32;
        #pragma unroll
        for (int i = 0; i < 4; ++i) {
            int e = i * 256 + t;
            int lm = e >> 5, ld = e & 31;
            int m = m0 + lm;
            tile[lm][ld] = (m < M_TOK) ? x[(size_t)m * DM + d0 + ld] : 0.0f;
        }
        __syncthreads();
        #pragma unroll
        for (int i = 0; i < 4; ++i) {
            int e = i * 256 + t;
            int ld = e >> 5, lm = e & 31;
            xT[(size_t)(d0 + ld) * M_PAD + m0 + lm] = tile[lm][ld];
        }
        return;
    }
    // ---- meta: h = relu(ct@W1^T + b1) (f32 out), Qb = x@b2resh^T — via bf16 MFMA ----
    __shared__ unsigned short AB[128 * 128];   // 32KB: ct_bf then x_bf, swizzled
    __shared__ unsigned short WB[64 * 128];    // 16KB: W1b / b2b chunk, swizzled
    const int m0 = (bid - 3296) * 128;
    const int w = t >> 6, l = t & 63;
    const int lr = l & 15, g = l >> 4;

    #pragma unroll
    for (int it = 0; it < 8; ++it) {
        int r = (t >> 4) + it * 16;
        int gg = t & 15;
        int m = m0 + r;
        f32x4 a = (f32x4)(0.0f), b = (f32x4)(0.0f);
        if (m < M_TOK) {
            a = *reinterpret_cast<const f32x4*>(&ct[(size_t)m * DM + gg * 8]);
            b = *reinterpret_cast<const f32x4*>(&ct[(size_t)m * DM + gg * 8 + 4]);
        }
        u32x4 pk;
        pk[0] = pk_bf2(a[0], a[1]); pk[1] = pk_bf2(a[2], a[3]);
        pk[2] = pk_bf2(b[0], b[1]); pk[3] = pk_bf2(b[2], b[3]);
        *reinterpret_cast<u32x4*>(&AB[r * 128 + ((gg ^ (r & 7)) * 8)]) = pk;
    }

    for (int jc = 0; jc < 4; ++jc) {
        __syncthreads();
        #pragma unroll
        for (int it = 0; it < 4; ++it) {
            int r = (t >> 4) + it * 16;
            int gg = t & 15;
            const float* src = &W1[(size_t)(jc * 64 + r) * DM + gg * 8];
            f32x4 a = *reinterpret_cast<const f32x4*>(src);
            f32x4 b = *reinterpret_cast<const f32x4*>(src + 4);
            u32x4 pk;
            pk[0] = pk_bf2(a[0], a[1]); pk[1] = pk_bf2(a[2], a[3]);
            pk[2] = pk_bf2(b[0], b[1]); pk[3] = pk_bf2(b[2], b[3]);
            *reinterpret_cast<u32x4*>(&WB[r * 128 + ((gg ^ (r & 7)) * 8)]) = pk;
        }
        __syncthreads();
        f32x4 acc[2][4];
        #pragma unroll
        for (int a2 = 0; a2 < 2; ++a2)
            #pragma unroll
            for (int jf = 0; jf < 4; ++jf) acc[a2][jf] = (f32x4)(0.0f);
        #pragma unroll
        for (int ks = 0; ks < 4; ++ks) {
            bf16x8 A2[2], B4[4];
            #pragma unroll
            for (int tf = 0; tf < 2; ++tf) {
                int row = (2 * w + tf) * 16 + lr;
                A2[tf] = *reinterpret_cast<const bf16x8*>(
                    &AB[row * 128 + (((ks * 4 + g) ^ (row & 7)) * 8)]);
            }
            #pragma unroll
            for (int jf = 0; jf < 4; ++jf) {
                int row = jf * 16 + lr;
                B4[jf] = *reinterpret_cast<const bf16x8*>(
                    &WB[row * 128 + (((ks * 4 + g) ^ (row & 7)) * 8)]);
            }
            #pragma unroll
            for (int tf = 0; tf < 2; ++tf)
                #pragma unroll
                for (int jf = 0; jf < 4; ++jf)
                    acc[tf][jf] = __builtin_amdgcn_mfma_f32_16x16x32_bf16(
                        A2[tf], B4[jf], acc[tf][jf], 0, 0, 0);
        }
        #pragma unroll
        for (int jf = 0; jf < 4; ++jf) {
            int j = jc * 64 + jf * 16 + lr;
            float bv = b1[j];
            #pragma unroll
            for (int tf = 0; tf < 2; ++tf)
                #pragma unroll
                for (int rr = 0; rr < 4; ++rr) {
                    int m = m0 + (2 * w + tf) * 16 + g * 4 + rr;
                    if (m < M_TOK)
                        hb[(size_t)m * DHID + j] = fmaxf(acc[tf][jf][rr] + bv, 0.0f);
                }
        }
    }

    __syncthreads();
    #pragma unroll
    for (int it = 0; it < 8; ++it) {
        int r = (t >> 4) + it * 16;
        int gg = t & 15;
        int m = m0 + r;
        f32x4 a = (f32x4)(0.0f), b = (f32x4)(0.0f);
        if (m < M_TOK) {
            a = *reinterpret_cast<const f32x4*>(&x[(size_t)m * DM + gg * 8]);
            b = *reinterpret_cast<const f32x4*>(&x[(size_t)m * DM + gg * 8 + 4]);
        }
        u32x4 pk;
        pk[0] = pk_bf2(a[0], a[1]); pk[1] = pk_bf2(a[2], a[3]);
        pk[2] = pk_bf2(b[0], b[1]); pk[3] = pk_bf2(b[2], b[3]);
        *reinterpret_cast<u32x4*>(&AB[r * 128 + ((gg ^ (r & 7)) * 8)]) = pk;
    }
    for (int oc = 0; oc < 2; ++oc) {
        #pragma unroll
        for (int it = 0; it < 4; ++it) {
            int r = (t >> 4) + it * 16;
            int gg = t & 15;
            const float* src = &b2[(size_t)(oc * 64 + r) * DM + gg * 8];
            f32x4 a = *reinterpret_cast<const f32x4*>(src);
            f32x4 b = *reinterpret_cast<const f32x4*>(src + 4);
            u32x4 pk;
            pk[0] = pk_bf2(a[0], a[1]); pk[1] = pk_bf2(a[2], a[3]);
            pk[2] = pk_bf2(b[0], b[1]); pk[3] = pk_bf2(b[2], b[3]);
            *reinterpret_cast<u32x4*>(&WB[r * 128 + ((gg ^ (r & 7)) * 8)]) = pk;
        }
        __syncthreads();
        f32x4 acc[2][4];
        #pragma unroll
        for (int a2 = 0; a2 < 2; ++a2)
            #pragma unroll
            for (int of = 0; of < 4; ++of) acc[a2][of] = (f32x4)(0.0f);
        #pragma unroll
        for (int ks = 0; ks < 4; ++ks) {
            bf16x8 A2[2], B4[4];
            #pragma unroll
            for (int tf = 0; tf < 2; ++tf) {
                int row = (2 * w + tf) * 16 + lr;
                A2[tf] = *reinterpret_cast<const bf16x8*>(
                    &AB[row * 128 + (((ks * 4 + g) ^ (row & 7)) * 8)]);
            }
            #pragma unroll
            for (int of = 0; of < 4; ++of) {
                int row = of * 16 + lr;
                B4[of] = *reinterpret_cast<const bf16x8*>(
                    &WB[row * 128 + (((ks * 4 + g) ^ (row & 7)) * 8)]);
            }
            #pragma unroll
            for (int tf = 0; tf < 2; ++tf)
                #pragma unroll
                for (int of = 0; of < 4; ++of)
                    acc[tf][of] = __builtin_amdgcn_mfma_f32_16x16x32_bf16(
                        A2[tf], B4[of], acc[tf][of], 0, 0, 0);
        }
        #pragma unroll
        for (int of = 0; of < 4; ++of) {
            int o = oc * 64 + of * 16 + lr;
            #pragma unroll
            for (int tf = 0; tf < 2; ++tf)
                #pragma unroll
                for (int rr = 0; rr < 4; ++rr) {
                    int m = m0 + (2 * w + tf) * 16 + g * 4 + rr;
                    if (m < M_TOK) Qb[(size_t)m * DM + o] = acc[tf][of][rr];
                }
        }
        __syncthreads();
    }
}

// ---------------- bilinear GEMM (r2-verified 121us structure) + cvt_pk pack ------------
// Q[m,o] = sum_{d,j} bf16(x[m,d]*h[m,j]) * bf16(W2[o*128+d, j])
// 64m x 128o blocks, 128 d-steps, dbuf LDS, XOR swizzle (0 conflicts, r2-measured),
// STAGE pack now 8 mul + 4 v_cvt_pk_bf16_f32 (was ~40 VALU of scalar bf16 emulation).
__global__ __launch_bounds__(256, 4) void k_gemm(const unsigned short* __restrict__ W2b,
                                                 const float* __restrict__ hbuf,
                                                 const float* __restrict__ xT,
                                                 float* __restrict__ Qp) {
    __shared__ unsigned short As[2][64 * 32];    // 4KB each
    __shared__ unsigned short Bs[2][128 * 32];   // 8KB each
    const int t = threadIdx.x;
    const int kid = blockIdx.x & 7;      // j-split -> XCD (round-robin dispatch)
    const int mb  = blockIdx.x >> 3;
    const int m0 = mb * 64;
    const int j0 = kid * 32;
    const int w = t >> 6;                // wave 0..3 owns o-range w*32
    const int l = t & 63;
    const int obase = w * 32;
    const int ro = t >> 2;               // staging row 0..63
    const int c2 = t & 3;                // staging granule

    const float* hrow = &hbuf[(size_t)(m0 + ro) * DHID + j0 + c2 * 8];
    const f32x4 ha  = *reinterpret_cast<const f32x4*>(hrow);
    const f32x4 hb4 = *reinterpret_cast<const f32x4*>(hrow + 4);

    f32x4 acc[4][2];
    #pragma unroll
    for (int mt = 0; mt < 4; ++mt) {
        acc[mt][0] = (f32x4)(0.0f);
        acc[mt][1] = (f32x4)(0.0f);
    }

    const int awOff = ro * 32 + ((c2 ^ ((ro >> 1) & 3)) * 8);
    const int lr = l & 15;
    const int g  = l >> 4;
    const int aBase = lr * 32 + ((g ^ ((lr >> 1) & 3)) * 8);

    const unsigned short* Bsrc = W2b + (size_t)j0 + c2 * 8;
    const size_t boff0 = (size_t)ro * 32768;
    const size_t boff1 = (size_t)(64 + ro) * 32768;

#define STAGE(BUF, BV0, BV1, XV) do {                              \
        u32x4 av_;                                                 \
        av_[0] = cvt_pk_bf16((XV) * ha[0],  (XV) * ha[1]);         \
        av_[1] = cvt_pk_bf16((XV) * ha[2],  (XV) * ha[3]);         \
        av_[2] = cvt_pk_bf16((XV) * hb4[0], (XV) * hb4[1]);        \
        av_[3] = cvt_pk_bf16((XV) * hb4[2], (XV) * hb4[3]);        \
        *reinterpret_cast<u32x4*>(&As[BUF][awOff]) = av_;          \
        *reinterpret_cast<u32x4*>(&Bs[BUF][awOff]) = (BV0);        \
        *reinterpret_cast<u32x4*>(&Bs[BUF][awOff + 2048]) = (BV1); \
    } while (0)

    // prologue: stage d=0 into buf0; prefetch d=1
    {
        u32x4 bv0 = *reinterpret_cast<const u32x4*>(Bsrc + boff0);
        u32x4 bv1 = *reinterpret_cast<const u32x4*>(Bsrc + boff1);
        float xv  = xT[m0 + ro];
        STAGE(0, bv0, bv1, xv);
    }
    u32x4 nbv0 = *reinterpret_cast<const u32x4*>(Bsrc + boff0 + 256);
    u32x4 nbv1 = *reinterpret_cast<const u32x4*>(Bsrc + boff1 + 256);
    float nxv  = xT[(size_t)M_PAD + m0 + ro];
    __syncthreads();

    int cur = 0;
    for (int d = 0; d < 128; ++d) {
        u32x4 afr0 = *reinterpret_cast<const u32x4*>(&As[cur][aBase]);
        u32x4 afr1 = *reinterpret_cast<const u32x4*>(&As[cur][aBase + 512]);
        u32x4 afr2 = *reinterpret_cast<const u32x4*>(&As[cur][aBase + 1024]);
        u32x4 afr3 = *reinterpret_cast<const u32x4*>(&As[cur][aBase + 1536]);
        u32x4 bfr0 = *reinterpret_cast<const u32x4*>(&Bs[cur][obase * 32 + aBase]);
        u32x4 bfr1 = *reinterpret_cast<const u32x4*>(&Bs[cur][obase * 32 + 512 + aBase]);
        if (d < 127) STAGE(cur ^ 1, nbv0, nbv1, nxv);
        if (d < 126) {
            nbv0 = *reinterpret_cast<const u32x4*>(Bsrc + boff0 + (size_t)(d + 2) * 256);
            nbv1 = *reinterpret_cast<const u32x4*>(Bsrc + boff1 + (size_t)(d + 2) * 256);
            nxv  = xT[(size_t)(d + 2) * M_PAD + m0 + ro];
        }
        __builtin_amdgcn_s_setprio(1);
        asm("v_mfma_f32_16x16x32_bf16 %0, %1, %2, %0" : "+v"(acc[0][0]) : "v"(afr0), "v"(bfr0));
        asm("v_mfma_f32_16x16x32_bf16 %0, %1, %2, %0" : "+v"(acc[0][1]) : "v"(afr0), "v"(bfr1));
        asm("v_mfma_f32_16x16x32_bf16 %0, %1, %2, %0" : "+v"(acc[1][0]) : "v"(afr1), "v"(bfr0));
        asm("v_mfma_f32_16x16x32_bf16 %0, %1, %2, %0" : "+v"(acc[1][1]) : "v"(afr1), "v"(bfr1));
        asm("v_mfma_f32_16x16x32_bf16 %0, %1, %2, %0" : "+v"(acc[2][0]) : "v"(afr2), "v"(bfr0));
        asm("v_mfma_f32_16x16x32_bf16 %0, %1, %2, %0" : "+v"(acc[2][1]) : "v"(afr2), "v"(bfr1));
        asm("v_mfma_f32_16x16x32_bf16 %0, %1, %2, %0" : "+v"(acc[3][0]) : "v"(afr3), "v"(bfr0));
        asm("v_mfma_f32_16x16x32_bf16 %0, %1, %2, %0" : "+v"(acc[3][1]) : "v"(afr3), "v"(bfr1));
        __builtin_amdgcn_s_setprio(0);
        __syncthreads();
        cur ^= 1;
    }
#undef STAGE

    // epilogue: D layout col(o) = lane&15, row(m) = (lane>>4)*4 + reg
    float* outp = Qp + (size_t)kid * M_PAD * DM;
    #pragma unroll
    for (int mt = 0; mt < 4; ++mt)
        #pragma unroll
        for (int ot = 0; ot < 2; ++ot)
            #pragma unroll
            for (int r = 0; r < 4; ++r) {
                int m = m0 + mt * 16 + g * 4 + r;
                int o = obase + ot * 16 + lr;
                outp[(size_t)m * DM + o] = acc[mt][ot][r];
            }
}

// ---------------- attention + W_out(global-stream) + residual + layernorm ----------------
// (r7-verified)
__global__ __launch_bounds__(256) void k_attn(const float* __restrict__ Qp,
                                              const float* __restrict__ Qb,
                                              const float* __restrict__ Kenc,
                                              const float* __restrict__ Venc,
                                              const float* __restrict__ xin,
                                              const float* __restrict__ Wout,
                                              const float* __restrict__ gamma,
                                              const float* __restrict__ beta,
                                              float* __restrict__ out) {
    __shared__ float Qs[12][132];
    __shared__ float Ks[12][132];
    __shared__ float Vs[12][132];
    __shared__ float Ss[12][12][8];
    __shared__ float Os[12][132];
    const int t = threadIdx.x;
    const int b = blockIdx.x / NN_;
    const int n = blockIdx.x % NN_;

    for (int e = t; e < 384; e += 256) {
        int row = e >> 5, c4 = e & 31;
        size_t mrow = (size_t)(b * NP + row) * NN_ + n;
        f32x4 q = *reinterpret_cast<const f32x4*>(&Qb[mrow * DM + c4 * 4]);
        #pragma unroll
        for (int k = 0; k < KSPLIT; ++k)
            q += *reinterpret_cast<const f32x4*>(&Qp[((size_t)k * M_PAD + mrow) * DM + c4 * 4]);
        *reinterpret_cast<f32x4*>(&Qs[row][c4 * 4]) = q;
        *reinterpret_cast<f32x4*>(&Ks[row][c4 * 4]) =
            *reinterpret_cast<const f32x4*>(&Kenc[mrow * DM + c4 * 4]);
        *reinterpret_cast<f32x4*>(&Vs[row][c4 * 4]) =
            *reinterpret_cast<const f32x4*>(&Venc[mrow * DM + c4 * 4]);
    }
    __syncthreads();
    if (t < 144) {
        int q = t / 12, p = t % 12;
        #pragma unroll
        for (int hh = 0; hh < 8; ++hh) {
            const f32x4* qv = reinterpret_cast<const f32x4*>(&Qs[q][hh * 16]);
            const f32x4* kv = reinterpret_cast<const f32x4*>(&Ks[p][hh * 16]);
            float s = 0.0f;
            #pragma unroll
            for (int c = 0; c < 4; ++c) {
                f32x4 a = qv[c], bb = kv[c];
                s += a[0] * bb[0] + a[1] * bb[1] + a[2] * bb[2] + a[3] * bb[3];
            }
            Ss[q][p][hh] = s * 0.25f;
        }
    }
    __syncthreads();
    if (t < 96) {
        int q = t >> 3, hh = t & 7;
        float mx = -1e30f;
        #pragma unroll
        for (int p = 0; p < 12; ++p) mx = fmaxf(mx, Ss[q][p][hh]);
        float ev[12]; float sum = 0.0f;
        #pragma unroll
        for (int p = 0; p < 12; ++p) { ev[p] = __expf(Ss[q][p][hh] - mx); sum += ev[p]; }
        float inv = 1.0f / sum;
        #pragma unroll
        for (int p = 0; p < 12; ++p) Ss[q][p][hh] = ev[p] * inv;
    }
    __syncthreads();
    #pragma unroll
    for (int i = 0; i < 6; ++i) {
        int e = i * 256 + t;
        int q = e >> 7, hk = e & 127, hh = hk >> 4;
        float acc = 0.0f;
        #pragma unroll
        for (int p = 0; p < 12; ++p) acc += Ss[q][p][hh] * Vs[p][hk];
        Os[q][hk] = acc;
    }
    __syncthreads();
    {
        const int o  = t & 127;
        const int qh = (t >> 7) * 6;
        const f32x4* wrow = reinterpret_cast<const f32x4*>(&Wout[(size_t)o * DM]);
        float pacc[6] = {0, 0, 0, 0, 0, 0};
        for (int c = 0; c < 32; ++c) {
            f32x4 wv = wrow[c];
            #pragma unroll
            for (int qq = 0; qq < 6; ++qq) {
                f32x4 ov = *reinterpret_cast<const f32x4*>(&Os[qh + qq][c * 4]);
                pacc[qq] += wv[0] * ov[0] + wv[1] * ov[1] + wv[2] * ov[2] + wv[3] * ov[3];
            }
        }
        #pragma unroll
        for (int qq = 0; qq < 6; ++qq) {
            size_t mrow = (size_t)(b * NP + qh + qq) * NN_ + n;
            Qs[qh + qq][o] = pacc[qq] + xin[mrow * DM + o];
        }
    }
    __syncthreads();
    const int wv_ = t >> 6, ll = t & 63;
    for (int rq = wv_; rq < 12; rq += 4) {
        float v0 = Qs[rq][ll], v1 = Qs[rq][ll + 64];
        float s = v0 + v1, ss = v0 * v0 + v1 * v1;
        #pragma unroll
        for (int msk = 1; msk < 64; msk <<= 1) {
            s += __shfl_xor(s, msk, 64);
            ss += __shfl_xor(ss, msk, 64);
        }
        float mu = s * (1.0f / 128.0f);
        float var = ss * (1.0f / 128.0f) - mu * mu;
        float rs = rsqrtf(var + 1e-5f);
        size_t mrow = (size_t)(b * NP + rq) * NN_ + n;
        out[mrow * DM + ll]      = (v0 - mu) * rs * gamma[ll] + beta[ll];
        out[mrow * DM + ll + 64] = (v1 - mu) * rs * gamma[ll + 64] + beta[ll + 64];
    }
}

// ---------------- launcher ----------------
extern "C" void kernel_launch(void* const* d_in, const int* in_sizes, int n_in,
                              void* d_out, int out_size, void* d_ws, size_t ws_size,
                              hipStream_t stream) {
    const float* xin   = (const float*)d_in[0];
    const float* Kenc  = (const float*)d_in[1];
    const float* Venc  = (const float*)d_in[2];
    const float* ct    = (const float*)d_in[3];
    const float* W1    = (const float*)d_in[4];
    const float* b1    = (const float*)d_in[5];
    const float* W2    = (const float*)d_in[6];
    const float* b2    = (const float*)d_in[7];
    const float* Wout  = (const float*)d_in[8];
    const float* gamma = (const float*)d_in[9];
    const float* beta  = (const float*)d_in[10];
    float* out = (float*)d_out;

    char* ws = (char*)d_ws;
    unsigned short* W2b = (unsigned short*)(ws);                  //  8,388,608 B
    float* xT  = (float*)(ws + 8388608);                          //  5,111,808 B (128 x 9984)
    float* hb  = (float*)(ws + 13500416);                         // 10,223,616 B (9984 x 256)
    float* Qb  = (float*)(ws + 23724032);                         //  5,111,808 B
    float* Qp  = (float*)(ws + 28835840);                         // 40,894,464 B (8 x 9984 x 128)

    hipLaunchKernelGGL(k_prep, dim3(3374), dim3(256), 0, stream,
                       W2, W2b, xin, xT, ct, W1, b1, b2, hb, Qb);
    hipLaunchKernelGGL(k_gemm, dim3(1248), dim3(256), 0, stream, W2b, hb, xT, Qp);
    hipLaunchKernelGGL(k_attn, dim3(828),  dim3(256), 0, stream, Qp, Qb, Kenc, Venc,
                       xin, Wout, gamma, beta, out);
}

// Round 14
// 165.688 us; speedup vs baseline: 1.2795x; 1.0755x over previous
//
#include <hip/hip_runtime.h>
#include <hip/hip_bf16.h>

// Problem constants
#define NB    4
#define NP    12          // P1 == P == 12
#define NN_   207
#define DM    128         // d_model
#define DHID  256
#define M_TOK 9936        // NB*NP*NN_
#define M_PAD 9984        // padded to 78*128 (xT / hb / Qp row space)
#define KSPLIT 8          // j-splits (j-chunk = 32)

typedef float        f32x4 __attribute__((ext_vector_type(4)));
typedef unsigned int u32x4 __attribute__((ext_vector_type(4)));
typedef __bf16       bf16x8 __attribute__((ext_vector_type(8)));

static __device__ __forceinline__ unsigned int pk_bf2(float a, float b) {
    __hip_bfloat16 ba = __float2bfloat16(a);
    __hip_bfloat16 bb = __float2bfloat16(b);
    unsigned short ua = *reinterpret_cast<unsigned short*>(&ba);
    unsigned short ub = *reinterpret_cast<unsigned short*>(&bb);
    return (unsigned int)ua | ((unsigned int)ub << 16);
}
// hardware packed f32->bf16 (RNE), 1 instr per 2 elements (no builtin on gfx950).
static __device__ __forceinline__ unsigned int cvt_pk_bf16(float lo, float hi) {
    unsigned int r;
    asm("v_cvt_pk_bf16_f32 %0, %1, %2" : "=v"(r) : "v"(lo), "v"(hi));
    return r;
}

// ---------------- prep: W2->bf16 | transpose x->xT | meta-MFMA (h f32, Qb) ----------
// (byte-identical to round 13 — verified)
__global__ __launch_bounds__(256) void k_prep(const float* __restrict__ W2,
                                              unsigned short* __restrict__ W2b,
                                              const float* __restrict__ x,
                                              float* __restrict__ xT,
                                              const float* __restrict__ ct,
                                              const float* __restrict__ W1,
                                              const float* __restrict__ b1,
                                              const float* __restrict__ b2,
                                              float* __restrict__ hb,
                                              float* __restrict__ Qb) {
    const int t = threadIdx.x;
    const int bid = blockIdx.x;
    if (bid < 2048) {
        int i = bid * 256 + t;
        const f32x4* in = reinterpret_cast<const f32x4*>(W2);
        f32x4 v0 = in[2 * i], v1 = in[2 * i + 1];
        u32x4 o;
        o[0] = pk_bf2(v0[0], v0[1]);
        o[1] = pk_bf2(v0[2], v0[3]);
        o[2] = pk_bf2(v1[0], v1[1]);
        o[3] = pk_bf2(v1[2], v1[3]);
        reinterpret_cast<u32x4*>(W2b)[i] = o;
        return;
    }
    if (bid < 3296) {
        __shared__ float tile[32][33];
        const int b = bid - 2048;
        const int bm = b >> 2;
        const int bd = b & 3;
        const int m0 = bm * 32, d0 = bd * 32;
        #pragma unroll
        for (int i = 0; i < 4; ++i) {
            int e = i * 256 + t;
            int lm = e >> 5, ld = e & 31;
            int m = m0 + lm;
            tile[lm][ld] = (m < M_TOK) ? x[(size_t)m * DM + d0 + ld] : 0.0f;
        }
        __syncthreads();
        #pragma unroll
        for (int i = 0; i < 4; ++i) {
            int e = i * 256 + t;
            int ld = e >> 5, lm = e & 31;
            xT[(size_t)(d0 + ld) * M_PAD + m0 + lm] = tile[lm][ld];
        }
        return;
    }
    __shared__ unsigned short AB[128 * 128];
    __shared__ unsigned short WB[64 * 128];
    const int m0 = (bid - 3296) * 128;
    const int w = t >> 6, l = t & 63;
    const int lr = l & 15, g = l >> 4;

    #pragma unroll
    for (int it = 0; it < 8; ++it) {
        int r = (t >> 4) + it * 16;
        int gg = t & 15;
        int m = m0 + r;
        f32x4 a = (f32x4)(0.0f), b = (f32x4)(0.0f);
        if (m < M_TOK) {
            a = *reinterpret_cast<const f32x4*>(&ct[(size_t)m * DM + gg * 8]);
            b = *reinterpret_cast<const f32x4*>(&ct[(size_t)m * DM + gg * 8 + 4]);
        }
        u32x4 pk;
        pk[0] = pk_bf2(a[0], a[1]); pk[1] = pk_bf2(a[2], a[3]);
        pk[2] = pk_bf2(b[0], b[1]); pk[3] = pk_bf2(b[2], b[3]);
        *reinterpret_cast<u32x4*>(&AB[r * 128 + ((gg ^ (r & 7)) * 8)]) = pk;
    }

    for (int jc = 0; jc < 4; ++jc) {
        __syncthreads();
        #pragma unroll
        for (int it = 0; it < 4; ++it) {
            int r = (t >> 4) + it * 16;
            int gg = t & 15;
            const float* src = &W1[(size_t)(jc * 64 + r) * DM + gg * 8];
            f32x4 a = *reinterpret_cast<const f32x4*>(src);
            f32x4 b = *reinterpret_cast<const f32x4*>(src + 4);
            u32x4 pk;
            pk[0] = pk_bf2(a[0], a[1]); pk[1] = pk_bf2(a[2], a[3]);
            pk[2] = pk_bf2(b[0], b[1]); pk[3] = pk_bf2(b[2], b[3]);
            *reinterpret_cast<u32x4*>(&WB[r * 128 + ((gg ^ (r & 7)) * 8)]) = pk;
        }
        __syncthreads();
        f32x4 acc[2][4];
        #pragma unroll
        for (int a2 = 0; a2 < 2; ++a2)
            #pragma unroll
            for (int jf = 0; jf < 4; ++jf) acc[a2][jf] = (f32x4)(0.0f);
        #pragma unroll
        for (int ks = 0; ks < 4; ++ks) {
            bf16x8 A2[2], B4[4];
            #pragma unroll
            for (int tf = 0; tf < 2; ++tf) {
                int row = (2 * w + tf) * 16 + lr;
                A2[tf] = *reinterpret_cast<const bf16x8*>(
                    &AB[row * 128 + (((ks * 4 + g) ^ (row & 7)) * 8)]);
            }
            #pragma unroll
            for (int jf = 0; jf < 4; ++jf) {
                int row = jf * 16 + lr;
                B4[jf] = *reinterpret_cast<const bf16x8*>(
                    &WB[row * 128 + (((ks * 4 + g) ^ (row & 7)) * 8)]);
            }
            #pragma unroll
            for (int tf = 0; tf < 2; ++tf)
                #pragma unroll
                for (int jf = 0; jf < 4; ++jf)
                    acc[tf][jf] = __builtin_amdgcn_mfma_f32_16x16x32_bf16(
                        A2[tf], B4[jf], acc[tf][jf], 0, 0, 0);
        }
        #pragma unroll
        for (int jf = 0; jf < 4; ++jf) {
            int j = jc * 64 + jf * 16 + lr;
            float bv = b1[j];
            #pragma unroll
            for (int tf = 0; tf < 2; ++tf)
                #pragma unroll
                for (int rr = 0; rr < 4; ++rr) {
                    int m = m0 + (2 * w + tf) * 16 + g * 4 + rr;
                    if (m < M_TOK)
                        hb[(size_t)m * DHID + j] = fmaxf(acc[tf][jf][rr] + bv, 0.0f);
                }
        }
    }

    __syncthreads();
    #pragma unroll
    for (int it = 0; it < 8; ++it) {
        int r = (t >> 4) + it * 16;
        int gg = t & 15;
        int m = m0 + r;
        f32x4 a = (f32x4)(0.0f), b = (f32x4)(0.0f);
        if (m < M_TOK) {
            a = *reinterpret_cast<const f32x4*>(&x[(size_t)m * DM + gg * 8]);
            b = *reinterpret_cast<const f32x4*>(&x[(size_t)m * DM + gg * 8 + 4]);
        }
        u32x4 pk;
        pk[0] = pk_bf2(a[0], a[1]); pk[1] = pk_bf2(a[2], a[3]);
        pk[2] = pk_bf2(b[0], b[1]); pk[3] = pk_bf2(b[2], b[3]);
        *reinterpret_cast<u32x4*>(&AB[r * 128 + ((gg ^ (r & 7)) * 8)]) = pk;
    }
    for (int oc = 0; oc < 2; ++oc) {
        #pragma unroll
        for (int it = 0; it < 4; ++it) {
            int r = (t >> 4) + it * 16;
            int gg = t & 15;
            const float* src = &b2[(size_t)(oc * 64 + r) * DM + gg * 8];
            f32x4 a = *reinterpret_cast<const f32x4*>(src);
            f32x4 b = *reinterpret_cast<const f32x4*>(src + 4);
            u32x4 pk;
            pk[0] = pk_bf2(a[0], a[1]); pk[1] = pk_bf2(a[2], a[3]);
            pk[2] = pk_bf2(b[0], b[1]); pk[3] = pk_bf2(b[2], b[3]);
            *reinterpret_cast<u32x4*>(&WB[r * 128 + ((gg ^ (r & 7)) * 8)]) = pk;
        }
        __syncthreads();
        f32x4 acc[2][4];
        #pragma unroll
        for (int a2 = 0; a2 < 2; ++a2)
            #pragma unroll
            for (int of = 0; of < 4; ++of) acc[a2][of] = (f32x4)(0.0f);
        #pragma unroll
        for (int ks = 0; ks < 4; ++ks) {
            bf16x8 A2[2], B4[4];
            #pragma unroll
            for (int tf = 0; tf < 2; ++tf) {
                int row = (2 * w + tf) * 16 + lr;
                A2[tf] = *reinterpret_cast<const bf16x8*>(
                    &AB[row * 128 + (((ks * 4 + g) ^ (row & 7)) * 8)]);
            }
            #pragma unroll
            for (int of = 0; of < 4; ++of) {
                int row = of * 16 + lr;
                B4[of] = *reinterpret_cast<const bf16x8*>(
                    &WB[row * 128 + (((ks * 4 + g) ^ (row & 7)) * 8)]);
            }
            #pragma unroll
            for (int tf = 0; tf < 2; ++tf)
                #pragma unroll
                for (int of = 0; of < 4; ++of)
                    acc[tf][of] = __builtin_amdgcn_mfma_f32_16x16x32_bf16(
                        A2[tf], B4[of], acc[tf][of], 0, 0, 0);
        }
        #pragma unroll
        for (int of = 0; of < 4; ++of) {
            int o = oc * 64 + of * 16 + lr;
            #pragma unroll
            for (int tf = 0; tf < 2; ++tf)
                #pragma unroll
                for (int rr = 0; rr < 4; ++rr) {
                    int m = m0 + (2 * w + tf) * 16 + g * 4 + rr;
                    if (m < M_TOK) Qb[(size_t)m * DM + o] = acc[tf][of][rr];
                }
        }
        __syncthreads();
    }
}

// ---------------- bilinear GEMM, m-tile 128: 16 MFMA per wave per barrier window -------
// Q[m,o] = sum_{d,j} bf16(x[m,d]*h[m,j]) * bf16(W2[o*128+d, j])
// Block 128m x 128o (full output dim), 128 d-steps, dbuf LDS (32KB), XOR swizzle.
// Staging: thread owns row t>>1 (A-m-row AND B-o-row), 2 adjacent j-chunks; h = 16 f32
// in regs; pack = 16 mul + 8 v_cvt_pk_bf16_f32. Grid 78 x 8 = 624.
__global__ __launch_bounds__(256, 3) void k_gemm(const unsigned short* __restrict__ W2b,
                                                 const float* __restrict__ hbuf,
                                                 const float* __restrict__ xT,
                                                 float* __restrict__ Qp) {
    __shared__ unsigned short As[2][128 * 32];   // 8KB each
    __shared__ unsigned short Bs[2][128 * 32];   // 8KB each
    const int t = threadIdx.x;
    const int kid = blockIdx.x & 7;      // j-split -> XCD (round-robin dispatch)
    const int mb  = blockIdx.x >> 3;     // 0..77
    const int m0 = mb * 128;
    const int j0 = kid * 32;
    const int w = t >> 6, l = t & 63;
    const int obase = w * 32;            // wave owns o-range [obase, +32)
    const int lr = l & 15, g = l >> 4;

    // staging: row r = t>>1 (0..127), chunks c0 and c0+1
    const int r  = t >> 1;
    const int c0 = (t & 1) * 2;
    const int aw0 = r * 32 + ((c0 ^ ((r >> 1) & 3)) * 8);
    const int aw1 = r * 32 + (((c0 + 1) ^ ((r >> 1) & 3)) * 8);

    // h fragment: 16 f32 (j0 + c0*8 .. +16), constant over all 128 d-steps
    const float* hrow = &hbuf[(size_t)(m0 + r) * DHID + j0 + c0 * 8];
    const f32x4 h0 = *reinterpret_cast<const f32x4*>(hrow);
    const f32x4 h1 = *reinterpret_cast<const f32x4*>(hrow + 4);
    const f32x4 h2 = *reinterpret_cast<const f32x4*>(hrow + 8);
    const f32x4 h3 = *reinterpret_cast<const f32x4*>(hrow + 12);

    f32x4 acc[8][2];
    #pragma unroll
    for (int fo = 0; fo < 8; ++fo) {
        acc[fo][0] = (f32x4)(0.0f);
        acc[fo][1] = (f32x4)(0.0f);
    }

    // B source: o-row = r, od = r*128 + d; advance 256 shorts per d
    const unsigned short* bp0 = W2b + (size_t)r * 32768 + j0 + c0 * 8;
    const unsigned short* bp1 = bp0 + 8;
    const float* xp = xT + m0 + r;

    // read offsets
    const int rswz = (g ^ ((lr >> 1) & 3)) * 8;
    const int aBase = lr * 32 + rswz;                  // + fo*512
    const int bBase = obase * 32 + lr * 32 + rswz;     // + ot*512

#define STAGE(BUF, BV0, BV1, XV) do {                              \
        u32x4 a0_, a1_;                                            \
        a0_[0] = cvt_pk_bf16((XV) * h0[0], (XV) * h0[1]);          \
        a0_[1] = cvt_pk_bf16((XV) * h0[2], (XV) * h0[3]);          \
        a0_[2] = cvt_pk_bf16((XV) * h1[0], (XV) * h1[1]);          \
        a0_[3] = cvt_pk_bf16((XV) * h1[2], (XV) * h1[3]);          \
        a1_[0] = cvt_pk_bf16((XV) * h2[0], (XV) * h2[1]);          \
        a1_[1] = cvt_pk_bf16((XV) * h2[2], (XV) * h2[3]);          \
        a1_[2] = cvt_pk_bf16((XV) * h3[0], (XV) * h3[1]);          \
        a1_[3] = cvt_pk_bf16((XV) * h3[2], (XV) * h3[3]);          \
        *reinterpret_cast<u32x4*>(&As[BUF][aw0]) = a0_;            \
        *reinterpret_cast<u32x4*>(&As[BUF][aw1]) = a1_;            \
        *reinterpret_cast<u32x4*>(&Bs[BUF][aw0]) = (BV0);          \
        *reinterpret_cast<u32x4*>(&Bs[BUF][aw1]) = (BV1);          \
    } while (0)

    // prologue: stage d=0 into buf0; prefetch d=1
    {
        u32x4 bv0 = *reinterpret_cast<const u32x4*>(bp0);
        u32x4 bv1 = *reinterpret_cast<const u32x4*>(bp1);
        float xv  = xp[0];
        STAGE(0, bv0, bv1, xv);
    }
    u32x4 nbv0 = *reinterpret_cast<const u32x4*>(bp0 + 256);
    u32x4 nbv1 = *reinterpret_cast<const u32x4*>(bp1 + 256);
    float nxv  = xp[M_PAD];
    __syncthreads();

    int cur = 0;
    for (int d = 0; d < 128; ++d) {
        u32x4 bfr0 = *reinterpret_cast<const u32x4*>(&Bs[cur][bBase]);
        u32x4 bfr1 = *reinterpret_cast<const u32x4*>(&Bs[cur][bBase + 512]);
        if (d < 127) STAGE(cur ^ 1, nbv0, nbv1, nxv);
        if (d < 126) {
            nbv0 = *reinterpret_cast<const u32x4*>(bp0 + (size_t)(d + 2) * 256);
            nbv1 = *reinterpret_cast<const u32x4*>(bp1 + (size_t)(d + 2) * 256);
            nxv  = xp[(size_t)(d + 2) * M_PAD];
        }
        __builtin_amdgcn_s_setprio(1);
        #pragma unroll
        for (int fo = 0; fo < 8; ++fo) {
            u32x4 afr = *reinterpret_cast<const u32x4*>(&As[cur][aBase + fo * 512]);
            asm("v_mfma_f32_16x16x32_bf16 %0, %1, %2, %0" : "+v"(acc[fo][0]) : "v"(afr), "v"(bfr0));
            asm("v_mfma_f32_16x16x32_bf16 %0, %1, %2, %0" : "+v"(acc[fo][1]) : "v"(afr), "v"(bfr1));
        }
        __builtin_amdgcn_s_setprio(0);
        __syncthreads();
        cur ^= 1;
    }
#undef STAGE

    // epilogue: D layout col(o) = lane&15, row(m) = (lane>>4)*4 + reg
    float* outp = Qp + (size_t)kid * M_PAD * DM;
    #pragma unroll
    for (int fo = 0; fo < 8; ++fo)
        #pragma unroll
        for (int ot = 0; ot < 2; ++ot)
            #pragma unroll
            for (int rr = 0; rr < 4; ++rr) {
                int m = m0 + fo * 16 + g * 4 + rr;
                int o = obase + ot * 16 + lr;
                outp[(size_t)m * DM + o] = acc[fo][ot][rr];
            }
}

// ---------------- attention + W_out(global-stream) + residual + layernorm ----------------
// (byte-identical to round 13 — verified)
__global__ __launch_bounds__(256) void k_attn(const float* __restrict__ Qp,
                                              const float* __restrict__ Qb,
                                              const float* __restrict__ Kenc,
                                              const float* __restrict__ Venc,
                                              const float* __restrict__ xin,
                                              const float* __restrict__ Wout,
                                              const float* __restrict__ gamma,
                                              const float* __restrict__ beta,
                                              float* __restrict__ out) {
    __shared__ float Qs[12][132];
    __shared__ float Ks[12][132];
    __shared__ float Vs[12][132];
    __shared__ float Ss[12][12][8];
    __shared__ float Os[12][132];
    const int t = threadIdx.x;
    const int b = blockIdx.x / NN_;
    const int n = blockIdx.x % NN_;

    for (int e = t; e < 384; e += 256) {
        int row = e >> 5, c4 = e & 31;
        size_t mrow = (size_t)(b * NP + row) * NN_ + n;
        f32x4 q = *reinterpret_cast<const f32x4*>(&Qb[mrow * DM + c4 * 4]);
        #pragma unroll
        for (int k = 0; k < KSPLIT; ++k)
            q += *reinterpret_cast<const f32x4*>(&Qp[((size_t)k * M_PAD + mrow) * DM + c4 * 4]);
        *reinterpret_cast<f32x4*>(&Qs[row][c4 * 4]) = q;
        *reinterpret_cast<f32x4*>(&Ks[row][c4 * 4]) =
            *reinterpret_cast<const f32x4*>(&Kenc[mrow * DM + c4 * 4]);
        *reinterpret_cast<f32x4*>(&Vs[row][c4 * 4]) =
            *reinterpret_cast<const f32x4*>(&Venc[mrow * DM + c4 * 4]);
    }
    __syncthreads();
    if (t < 144) {
        int q = t / 12, p = t % 12;
        #pragma unroll
        for (int hh = 0; hh < 8; ++hh) {
            const f32x4* qv = reinterpret_cast<const f32x4*>(&Qs[q][hh * 16]);
            const f32x4* kv = reinterpret_cast<const f32x4*>(&Ks[p][hh * 16]);
            float s = 0.0f;
            #pragma unroll
            for (int c = 0; c < 4; ++c) {
                f32x4 a = qv[c], bb = kv[c];
                s += a[0] * bb[0] + a[1] * bb[1] + a[2] * bb[2] + a[3] * bb[3];
            }
            Ss[q][p][hh] = s * 0.25f;
        }
    }
    __syncthreads();
    if (t < 96) {
        int q = t >> 3, hh = t & 7;
        float mx = -1e30f;
        #pragma unroll
        for (int p = 0; p < 12; ++p) mx = fmaxf(mx, Ss[q][p][hh]);
        float ev[12]; float sum = 0.0f;
        #pragma unroll
        for (int p = 0; p < 12; ++p) { ev[p] = __expf(Ss[q][p][hh] - mx); sum += ev[p]; }
        float inv = 1.0f / sum;
        #pragma unroll
        for (int p = 0; p < 12; ++p) Ss[q][p][hh] = ev[p] * inv;
    }
    __syncthreads();
    #pragma unroll
    for (int i = 0; i < 6; ++i) {
        int e = i * 256 + t;
        int q = e >> 7, hk = e & 127, hh = hk >> 4;
        float acc = 0.0f;
        #pragma unroll
        for (int p = 0; p < 12; ++p) acc += Ss[q][p][hh] * Vs[p][hk];
        Os[q][hk] = acc;
    }
    __syncthreads();
    {
        const int o  = t & 127;
        const int qh = (t >> 7) * 6;
        const f32x4* wrow = reinterpret_cast<const f32x4*>(&Wout[(size_t)o * DM]);
        float pacc[6] = {0, 0, 0, 0, 0, 0};
        for (int c = 0; c < 32; ++c) {
            f32x4 wv = wrow[c];
            #pragma unroll
            for (int qq = 0; qq < 6; ++qq) {
                f32x4 ov = *reinterpret_cast<const f32x4*>(&Os[qh + qq][c * 4]);
                pacc[qq] += wv[0] * ov[0] + wv[1] * ov[1] + wv[2] * ov[2] + wv[3] * ov[3];
            }
        }
        #pragma unroll
        for (int qq = 0; qq < 6; ++qq) {
            size_t mrow = (size_t)(b * NP + qh + qq) * NN_ + n;
            Qs[qh + qq][o] = pacc[qq] + xin[mrow * DM + o];
        }
    }
    __syncthreads();
    const int wv_ = t >> 6, ll = t & 63;
    for (int rq = wv_; rq < 12; rq += 4) {
        float v0 = Qs[rq][ll], v1 = Qs[rq][ll + 64];
        float s = v0 + v1, ss = v0 * v0 + v1 * v1;
        #pragma unroll
        for (int msk = 1; msk < 64; msk <<= 1) {
            s += __shfl_xor(s, msk, 64);
            ss += __shfl_xor(ss, msk, 64);
        }
        float mu = s * (1.0f / 128.0f);
        float var = ss * (1.0f / 128.0f) - mu * mu;
        float rs = rsqrtf(var + 1e-5f);
        size_t mrow = (size_t)(b * NP + rq) * NN_ + n;
        out[mrow * DM + ll]      = (v0 - mu) * rs * gamma[ll] + beta[ll];
        out[mrow * DM + ll + 64] = (v1 - mu) * rs * gamma[ll + 64] + beta[ll + 64];
    }
}

// ---------------- launcher ----------------
extern "C" void kernel_launch(void* const* d_in, const int* in_sizes, int n_in,
                              void* d_out, int out_size, void* d_ws, size_t ws_size,
                              hipStream_t stream) {
    const float* xin   = (const float*)d_in[0];
    const float* Kenc  = (const float*)d_in[1];
    const float* Venc  = (const float*)d_in[2];
    const float* ct    = (const float*)d_in[3];
    const float* W1    = (const float*)d_in[4];
    const float* b1    = (const float*)d_in[5];
    const float* W2    = (const float*)d_in[6];
    const float* b2    = (const float*)d_in[7];
    const float* Wout  = (const float*)d_in[8];
    const float* gamma = (const float*)d_in[9];
    const float* beta  = (const float*)d_in[10];
    float* out = (float*)d_out;

    char* ws = (char*)d_ws;
    unsigned short* W2b = (unsigned short*)(ws);                  //  8,388,608 B
    float* xT  = (float*)(ws + 8388608);                          //  5,111,808 B (128 x 9984)
    float* hb  = (float*)(ws + 13500416);                         // 10,223,616 B (9984 x 256)
    float* Qb  = (float*)(ws + 23724032);                         //  5,111,808 B
    float* Qp  = (float*)(ws + 28835840);                         // 40,894,464 B (8 x 9984 x 128)

    hipLaunchKernelGGL(k_prep, dim3(3374), dim3(256), 0, stream,
                       W2, W2b, xin, xT, ct, W1, b1, b2, hb, Qb);
    hipLaunchKernelGGL(k_gemm, dim3(624), dim3(256), 0, stream, W2b, hb, xT, Qp);
    hipLaunchKernelGGL(k_attn, dim3(828), dim3(256), 0, stream, Qp, Qb, Kenc, Venc,
                       xin, Wout, gamma, beta, out);
}

// Round 15
// 150.407 us; speedup vs baseline: 1.4095x; 1.1016x over previous
//
#include <hip/hip_runtime.h>
#include <hip/hip_bf16.h>

// Problem constants
#define NB    4
#define NP    12          // P1 == P == 12
#define NN_   207
#define DM    128         // d_model
#define DHID  256
#define M_TOK 9936        // NB*NP*NN_
#define M_PAD 9984        // padded to 78*128 (xT / hb / Qp row space)
#define KSPLIT 8          // j-splits (j-chunk = 32)

typedef float        f32x4 __attribute__((ext_vector_type(4)));
typedef unsigned int u32x4 __attribute__((ext_vector_type(4)));
typedef __bf16       bf16x8 __attribute__((ext_vector_type(8)));

static __device__ __forceinline__ unsigned int pk_bf2(float a, float b) {
    __hip_bfloat16 ba = __float2bfloat16(a);
    __hip_bfloat16 bb = __float2bfloat16(b);
    unsigned short ua = *reinterpret_cast<unsigned short*>(&ba);
    unsigned short ub = *reinterpret_cast<unsigned short*>(&bb);
    return (unsigned int)ua | ((unsigned int)ub << 16);
}
// hardware packed f32->bf16 (RNE), 1 instr per 2 elements (no builtin on gfx950).
static __device__ __forceinline__ unsigned int cvt_pk_bf16(float lo, float hi) {
    unsigned int r;
    asm("v_cvt_pk_bf16_f32 %0, %1, %2" : "=v"(r) : "v"(lo), "v"(hi));
    return r;
}

// ---------------- prep: W2->bf16 | transpose x->xT | meta-MFMA (h f32, Qb) ----------
// (byte-identical to round 13/14 — verified)
__global__ __launch_bounds__(256) void k_prep(const float* __restrict__ W2,
                                              unsigned short* __restrict__ W2b,
                                              const float* __restrict__ x,
                                              float* __restrict__ xT,
                                              const float* __restrict__ ct,
                                              const float* __restrict__ W1,
                                              const float* __restrict__ b1,
                                              const float* __restrict__ b2,
                                              float* __restrict__ hb,
                                              float* __restrict__ Qb) {
    const int t = threadIdx.x;
    const int bid = blockIdx.x;
    if (bid < 2048) {
        int i = bid * 256 + t;
        const f32x4* in = reinterpret_cast<const f32x4*>(W2);
        f32x4 v0 = in[2 * i], v1 = in[2 * i + 1];
        u32x4 o;
        o[0] = pk_bf2(v0[0], v0[1]);
        o[1] = pk_bf2(v0[2], v0[3]);
        o[2] = pk_bf2(v1[0], v1[1]);
        o[3] = pk_bf2(v1[2], v1[3]);
        reinterpret_cast<u32x4*>(W2b)[i] = o;
        return;
    }
    if (bid < 3296) {
        __shared__ float tile[32][33];
        const int b = bid - 2048;
        const int bm = b >> 2;
        const int bd = b & 3;
        const int m0 = bm * 32, d0 = bd * 32;
        #pragma unroll
        for (int i = 0; i < 4; ++i) {
            int e = i * 256 + t;
            int lm = e >> 5, ld = e & 31;
            int m = m0 + lm;
            tile[lm][ld] = (m < M_TOK) ? x[(size_t)m * DM + d0 + ld] : 0.0f;
        }
        __syncthreads();
        #pragma unroll
        for (int i = 0; i < 4; ++i) {
            int e = i * 256 + t;
            int ld = e >> 5, lm = e & 31;
            xT[(size_t)(d0 + ld) * M_PAD + m0 + lm] = tile[lm][ld];
        }
        return;
    }
    __shared__ unsigned short AB[128 * 128];
    __shared__ unsigned short WB[64 * 128];
    const int m0 = (bid - 3296) * 128;
    const int w = t >> 6, l = t & 63;
    const int lr = l & 15, g = l >> 4;

    #pragma unroll
    for (int it = 0; it < 8; ++it) {
        int r = (t >> 4) + it * 16;
        int gg = t & 15;
        int m = m0 + r;
        f32x4 a = (f32x4)(0.0f), b = (f32x4)(0.0f);
        if (m < M_TOK) {
            a = *reinterpret_cast<const f32x4*>(&ct[(size_t)m * DM + gg * 8]);
            b = *reinterpret_cast<const f32x4*>(&ct[(size_t)m * DM + gg * 8 + 4]);
        }
        u32x4 pk;
        pk[0] = pk_bf2(a[0], a[1]); pk[1] = pk_bf2(a[2], a[3]);
        pk[2] = pk_bf2(b[0], b[1]); pk[3] = pk_bf2(b[2], b[3]);
        *reinterpret_cast<u32x4*>(&AB[r * 128 + ((gg ^ (r & 7)) * 8)]) = pk;
    }

    for (int jc = 0; jc < 4; ++jc) {
        __syncthreads();
        #pragma unroll
        for (int it = 0; it < 4; ++it) {
            int r = (t >> 4) + it * 16;
            int gg = t & 15;
            const float* src = &W1[(size_t)(jc * 64 + r) * DM + gg * 8];
            f32x4 a = *reinterpret_cast<const f32x4*>(src);
            f32x4 b = *reinterpret_cast<const f32x4*>(src + 4);
            u32x4 pk;
            pk[0] = pk_bf2(a[0], a[1]); pk[1] = pk_bf2(a[2], a[3]);
            pk[2] = pk_bf2(b[0], b[1]); pk[3] = pk_bf2(b[2], b[3]);
            *reinterpret_cast<u32x4*>(&WB[r * 128 + ((gg ^ (r & 7)) * 8)]) = pk;
        }
        __syncthreads();
        f32x4 acc[2][4];
        #pragma unroll
        for (int a2 = 0; a2 < 2; ++a2)
            #pragma unroll
            for (int jf = 0; jf < 4; ++jf) acc[a2][jf] = (f32x4)(0.0f);
        #pragma unroll
        for (int ks = 0; ks < 4; ++ks) {
            bf16x8 A2[2], B4[4];
            #pragma unroll
            for (int tf = 0; tf < 2; ++tf) {
                int row = (2 * w + tf) * 16 + lr;
                A2[tf] = *reinterpret_cast<const bf16x8*>(
                    &AB[row * 128 + (((ks * 4 + g) ^ (row & 7)) * 8)]);
            }
            #pragma unroll
            for (int jf = 0; jf < 4; ++jf) {
                int row = jf * 16 + lr;
                B4[jf] = *reinterpret_cast<const bf16x8*>(
                    &WB[row * 128 + (((ks * 4 + g) ^ (row & 7)) * 8)]);
            }
            #pragma unroll
            for (int tf = 0; tf < 2; ++tf)
                #pragma unroll
                for (int jf = 0; jf < 4; ++jf)
                    acc[tf][jf] = __builtin_amdgcn_mfma_f32_16x16x32_bf16(
                        A2[tf], B4[jf], acc[tf][jf], 0, 0, 0);
        }
        #pragma unroll
        for (int jf = 0; jf < 4; ++jf) {
            int j = jc * 64 + jf * 16 + lr;
            float bv = b1[j];
            #pragma unroll
            for (int tf = 0; tf < 2; ++tf)
                #pragma unroll
                for (int rr = 0; rr < 4; ++rr) {
                    int m = m0 + (2 * w + tf) * 16 + g * 4 + rr;
                    if (m < M_TOK)
                        hb[(size_t)m * DHID + j] = fmaxf(acc[tf][jf][rr] + bv, 0.0f);
                }
        }
    }

    __syncthreads();
    #pragma unroll
    for (int it = 0; it < 8; ++it) {
        int r = (t >> 4) + it * 16;
        int gg = t & 15;
        int m = m0 + r;
        f32x4 a = (f32x4)(0.0f), b = (f32x4)(0.0f);
        if (m < M_TOK) {
            a = *reinterpret_cast<const f32x4*>(&x[(size_t)m * DM + gg * 8]);
            b = *reinterpret_cast<const f32x4*>(&x[(size_t)m * DM + gg * 8 + 4]);
        }
        u32x4 pk;
        pk[0] = pk_bf2(a[0], a[1]); pk[1] = pk_bf2(a[2], a[3]);
        pk[2] = pk_bf2(b[0], b[1]); pk[3] = pk_bf2(b[2], b[3]);
        *reinterpret_cast<u32x4*>(&AB[r * 128 + ((gg ^ (r & 7)) * 8)]) = pk;
    }
    for (int oc = 0; oc < 2; ++oc) {
        #pragma unroll
        for (int it = 0; it < 4; ++it) {
            int r = (t >> 4) + it * 16;
            int gg = t & 15;
            const float* src = &b2[(size_t)(oc * 64 + r) * DM + gg * 8];
            f32x4 a = *reinterpret_cast<const f32x4*>(src);
            f32x4 b = *reinterpret_cast<const f32x4*>(src + 4);
            u32x4 pk;
            pk[0] = pk_bf2(a[0], a[1]); pk[1] = pk_bf2(a[2], a[3]);
            pk[2] = pk_bf2(b[0], b[1]); pk[3] = pk_bf2(b[2], b[3]);
            *reinterpret_cast<u32x4*>(&WB[r * 128 + ((gg ^ (r & 7)) * 8)]) = pk;
        }
        __syncthreads();
        f32x4 acc[2][4];
        #pragma unroll
        for (int a2 = 0; a2 < 2; ++a2)
            #pragma unroll
            for (int of = 0; of < 4; ++of) acc[a2][of] = (f32x4)(0.0f);
        #pragma unroll
        for (int ks = 0; ks < 4; ++ks) {
            bf16x8 A2[2], B4[4];
            #pragma unroll
            for (int tf = 0; tf < 2; ++tf) {
                int row = (2 * w + tf) * 16 + lr;
                A2[tf] = *reinterpret_cast<const bf16x8*>(
                    &AB[row * 128 + (((ks * 4 + g) ^ (row & 7)) * 8)]);
            }
            #pragma unroll
            for (int of = 0; of < 4; ++of) {
                int row = of * 16 + lr;
                B4[of] = *reinterpret_cast<const bf16x8*>(
                    &WB[row * 128 + (((ks * 4 + g) ^ (row & 7)) * 8)]);
            }
            #pragma unroll
            for (int tf = 0; tf < 2; ++tf)
                #pragma unroll
                for (int of = 0; of < 4; ++of)
                    acc[tf][of] = __builtin_amdgcn_mfma_f32_16x16x32_bf16(
                        A2[tf], B4[of], acc[tf][of], 0, 0, 0);
        }
        #pragma unroll
        for (int of = 0; of < 4; ++of) {
            int o = oc * 64 + of * 16 + lr;
            #pragma unroll
            for (int tf = 0; tf < 2; ++tf)
                #pragma unroll
                for (int rr = 0; rr < 4; ++rr) {
                    int m = m0 + (2 * w + tf) * 16 + g * 4 + rr;
                    if (m < M_TOK) Qb[(size_t)m * DM + o] = acc[tf][of][rr];
                }
        }
        __syncthreads();
    }
}

// ---------------- bilinear GEMM, m-tile 160: balanced grid (504 = 1.97/CU) ------------
// Q[m,o] = sum_{d,j} bf16(x[m,d]*h[m,j]) * bf16(W2[o*128+d, j])
// Block 160m x 128o, 128 d-steps, dbuf LDS (36KB), XOR swizzle (verified pair).
// Staging: thread covers A rows t>>2, +64, (+128 if t<128 — wave-uniform), chunk t&3;
// B rows t>>2, +64. h = 16-24 f32 in regs; pack via v_cvt_pk_bf16_f32.
// 20 MFMA per wave per barrier window. Grid 63 x 8 = 504.
__global__ __launch_bounds__(256, 2) void k_gemm(const unsigned short* __restrict__ W2b,
                                                 const float* __restrict__ hbuf,
                                                 const float* __restrict__ xT,
                                                 float* __restrict__ Qp) {
    __shared__ unsigned short As[2][160 * 32];   // 10KB each
    __shared__ unsigned short Bs[2][128 * 32];   //  8KB each
    const int t = threadIdx.x;
    const int kid = blockIdx.x & 7;      // j-split -> XCD (round-robin dispatch)
    const int mb  = blockIdx.x >> 3;     // 0..62
    const int m0 = mb * 160;
    const int j0 = kid * 32;
    const int w = t >> 6, l = t & 63;
    const int obase = w * 32;            // wave owns o-range [obase, +32)
    const int lr = l & 15, g = l >> 4;

    // staging: base row rA = t>>2, chunk c = t&3; covers rows rA, rA+64, (rA+128 if t<128)
    const int rA = t >> 2;
    const int c  = t & 3;
    const bool has3 = (t < 128);         // wave-uniform (waves 0,1)
    const int aw = rA * 32 + ((c ^ ((rA >> 1) & 3)) * 8);   // +2048 per 64-row band

    // h fragments (constant over d): rows m0+rA, m0+64+rA, m0+128+rA; j0+c*8..+16? (8 j's)
    const float* h1p = &hbuf[(size_t)(m0 + rA) * DHID + j0 + c * 8];
    const float* h2p = &hbuf[(size_t)(m0 + 64 + rA) * DHID + j0 + c * 8];
    const f32x4 h1a = *reinterpret_cast<const f32x4*>(h1p);
    const f32x4 h1b = *reinterpret_cast<const f32x4*>(h1p + 4);
    const f32x4 h2a = *reinterpret_cast<const f32x4*>(h2p);
    const f32x4 h2b = *reinterpret_cast<const f32x4*>(h2p + 4);
    f32x4 h3a = (f32x4)(0.0f), h3b = (f32x4)(0.0f);
    if (has3) {
        const float* h3p = &hbuf[(size_t)(m0 + 128 + rA) * DHID + j0 + c * 8];
        h3a = *reinterpret_cast<const f32x4*>(h3p);
        h3b = *reinterpret_cast<const f32x4*>(h3p + 4);
    }

    f32x4 acc[10][2];
    #pragma unroll
    for (int fo = 0; fo < 10; ++fo) {
        acc[fo][0] = (f32x4)(0.0f);
        acc[fo][1] = (f32x4)(0.0f);
    }

    // B sources: o-rows rA and rA+64; od = o*128 + d -> advance 256 shorts per d
    const unsigned short* bp1 = W2b + (size_t)rA * 32768 + j0 + c * 8;
    const unsigned short* bp2 = bp1 + (size_t)64 * 32768;
    const float* xp = xT + m0 + rA;      // +64 / +128 for bands; advance M_PAD per d

    // read offsets
    const int rswz = (g ^ ((lr >> 1) & 3)) * 8;
    const int aBase = lr * 32 + rswz;                  // + fo*512
    const int bBase = obase * 32 + lr * 32 + rswz;     // + ot*512

#define STAGE(BUF, BV1, BV2, XV1, XV2, XV3) do {                       \
        u32x4 a_;                                                      \
        a_[0] = cvt_pk_bf16((XV1) * h1a[0], (XV1) * h1a[1]);           \
        a_[1] = cvt_pk_bf16((XV1) * h1a[2], (XV1) * h1a[3]);           \
        a_[2] = cvt_pk_bf16((XV1) * h1b[0], (XV1) * h1b[1]);           \
        a_[3] = cvt_pk_bf16((XV1) * h1b[2], (XV1) * h1b[3]);           \
        *reinterpret_cast<u32x4*>(&As[BUF][aw]) = a_;                  \
        a_[0] = cvt_pk_bf16((XV2) * h2a[0], (XV2) * h2a[1]);           \
        a_[1] = cvt_pk_bf16((XV2) * h2a[2], (XV2) * h2a[3]);           \
        a_[2] = cvt_pk_bf16((XV2) * h2b[0], (XV2) * h2b[1]);           \
        a_[3] = cvt_pk_bf16((XV2) * h2b[2], (XV2) * h2b[3]);           \
        *reinterpret_cast<u32x4*>(&As[BUF][aw + 2048]) = a_;           \
        if (has3) {                                                    \
            a_[0] = cvt_pk_bf16((XV3) * h3a[0], (XV3) * h3a[1]);       \
            a_[1] = cvt_pk_bf16((XV3) * h3a[2], (XV3) * h3a[3]);       \
            a_[2] = cvt_pk_bf16((XV3) * h3b[0], (XV3) * h3b[1]);       \
            a_[3] = cvt_pk_bf16((XV3) * h3b[2], (XV3) * h3b[3]);       \
            *reinterpret_cast<u32x4*>(&As[BUF][aw + 4096]) = a_;       \
        }                                                              \
        *reinterpret_cast<u32x4*>(&Bs[BUF][aw]) = (BV1);               \
        *reinterpret_cast<u32x4*>(&Bs[BUF][aw + 2048]) = (BV2);        \
    } while (0)

    // prologue: stage d=0 into buf0; prefetch d=1
    {
        u32x4 bv1 = *reinterpret_cast<const u32x4*>(bp1);
        u32x4 bv2 = *reinterpret_cast<const u32x4*>(bp2);
        float x1 = xp[0], x2 = xp[64], x3 = xp[128];
        STAGE(0, bv1, bv2, x1, x2, x3);
    }
    u32x4 nb1 = *reinterpret_cast<const u32x4*>(bp1 + 256);
    u32x4 nb2 = *reinterpret_cast<const u32x4*>(bp2 + 256);
    float nx1 = xp[M_PAD], nx2 = xp[M_PAD + 64], nx3 = xp[M_PAD + 128];
    __syncthreads();

    int cur = 0;
    for (int d = 0; d < 128; ++d) {
        u32x4 bfr0 = *reinterpret_cast<const u32x4*>(&Bs[cur][bBase]);
        u32x4 bfr1 = *reinterpret_cast<const u32x4*>(&Bs[cur][bBase + 512]);
        if (d < 127) STAGE(cur ^ 1, nb1, nb2, nx1, nx2, nx3);
        if (d < 126) {
            nb1 = *reinterpret_cast<const u32x4*>(bp1 + (size_t)(d + 2) * 256);
            nb2 = *reinterpret_cast<const u32x4*>(bp2 + (size_t)(d + 2) * 256);
            const float* xq = xp + (size_t)(d + 2) * M_PAD;
            nx1 = xq[0]; nx2 = xq[64]; nx3 = xq[128];
        }
        __builtin_amdgcn_s_setprio(1);
        #pragma unroll
        for (int fo = 0; fo < 10; ++fo) {
            u32x4 afr = *reinterpret_cast<const u32x4*>(&As[cur][aBase + fo * 512]);
            asm("v_mfma_f32_16x16x32_bf16 %0, %1, %2, %0" : "+v"(acc[fo][0]) : "v"(afr), "v"(bfr0));
            asm("v_mfma_f32_16x16x32_bf16 %0, %1, %2, %0" : "+v"(acc[fo][1]) : "v"(afr), "v"(bfr1));
        }
        __builtin_amdgcn_s_setprio(0);
        __syncthreads();
        cur ^= 1;
    }
#undef STAGE

    // epilogue: D layout col(o) = lane&15, row(m) = (lane>>4)*4 + reg
    float* outp = Qp + (size_t)kid * M_PAD * DM;
    #pragma unroll
    for (int fo = 0; fo < 10; ++fo)
        #pragma unroll
        for (int ot = 0; ot < 2; ++ot)
            #pragma unroll
            for (int rr = 0; rr < 4; ++rr) {
                int m = m0 + fo * 16 + g * 4 + rr;
                int o = obase + ot * 16 + lr;
                if (m < M_TOK) outp[(size_t)m * DM + o] = acc[fo][ot][rr];
            }
}

// ---------------- attention + W_out(global-stream) + residual + layernorm ----------------
// (byte-identical to round 13/14 — verified)
__global__ __launch_bounds__(256) void k_attn(const float* __restrict__ Qp,
                                              const float* __restrict__ Qb,
                                              const float* __restrict__ Kenc,
                                              const float* __restrict__ Venc,
                                              const float* __restrict__ xin,
                                              const float* __restrict__ Wout,
                                              const float* __restrict__ gamma,
                                              const float* __restrict__ beta,
                                              float* __restrict__ out) {
    __shared__ float Qs[12][132];
    __shared__ float Ks[12][132];
    __shared__ float Vs[12][132];
    __shared__ float Ss[12][12][8];
    __shared__ float Os[12][132];
    const int t = threadIdx.x;
    const int b = blockIdx.x / NN_;
    const int n = blockIdx.x % NN_;

    for (int e = t; e < 384; e += 256) {
        int row = e >> 5, c4 = e & 31;
        size_t mrow = (size_t)(b * NP + row) * NN_ + n;
        f32x4 q = *reinterpret_cast<const f32x4*>(&Qb[mrow * DM + c4 * 4]);
        #pragma unroll
        for (int k = 0; k < KSPLIT; ++k)
            q += *reinterpret_cast<const f32x4*>(&Qp[((size_t)k * M_PAD + mrow) * DM + c4 * 4]);
        *reinterpret_cast<f32x4*>(&Qs[row][c4 * 4]) = q;
        *reinterpret_cast<f32x4*>(&Ks[row][c4 * 4]) =
            *reinterpret_cast<const f32x4*>(&Kenc[mrow * DM + c4 * 4]);
        *reinterpret_cast<f32x4*>(&Vs[row][c4 * 4]) =
            *reinterpret_cast<const f32x4*>(&Venc[mrow * DM + c4 * 4]);
    }
    __syncthreads();
    if (t < 144) {
        int q = t / 12, p = t % 12;
        #pragma unroll
        for (int hh = 0; hh < 8; ++hh) {
            const f32x4* qv = reinterpret_cast<const f32x4*>(&Qs[q][hh * 16]);
            const f32x4* kv = reinterpret_cast<const f32x4*>(&Ks[p][hh * 16]);
            float s = 0.0f;
            #pragma unroll
            for (int c = 0; c < 4; ++c) {
                f32x4 a = qv[c], bb = kv[c];
                s += a[0] * bb[0] + a[1] * bb[1] + a[2] * bb[2] + a[3] * bb[3];
            }
            Ss[q][p][hh] = s * 0.25f;
        }
    }
    __syncthreads();
    if (t < 96) {
        int q = t >> 3, hh = t & 7;
        float mx = -1e30f;
        #pragma unroll
        for (int p = 0; p < 12; ++p) mx = fmaxf(mx, Ss[q][p][hh]);
        float ev[12]; float sum = 0.0f;
        #pragma unroll
        for (int p = 0; p < 12; ++p) { ev[p] = __expf(Ss[q][p][hh] - mx); sum += ev[p]; }
        float inv = 1.0f / sum;
        #pragma unroll
        for (int p = 0; p < 12; ++p) Ss[q][p][hh] = ev[p] * inv;
    }
    __syncthreads();
    #pragma unroll
    for (int i = 0; i < 6; ++i) {
        int e = i * 256 + t;
        int q = e >> 7, hk = e & 127, hh = hk >> 4;
        float acc = 0.0f;
        #pragma unroll
        for (int p = 0; p < 12; ++p) acc += Ss[q][p][hh] * Vs[p][hk];
        Os[q][hk] = acc;
    }
    __syncthreads();
    {
        const int o  = t & 127;
        const int qh = (t >> 7) * 6;
        const f32x4* wrow = reinterpret_cast<const f32x4*>(&Wout[(size_t)o * DM]);
        float pacc[6] = {0, 0, 0, 0, 0, 0};
        for (int c = 0; c < 32; ++c) {
            f32x4 wv = wrow[c];
            #pragma unroll
            for (int qq = 0; qq < 6; ++qq) {
                f32x4 ov = *reinterpret_cast<const f32x4*>(&Os[qh + qq][c * 4]);
                pacc[qq] += wv[0] * ov[0] + wv[1] * ov[1] + wv[2] * ov[2] + wv[3] * ov[3];
            }
        }
        #pragma unroll
        for (int qq = 0; qq < 6; ++qq) {
            size_t mrow = (size_t)(b * NP + qh + qq) * NN_ + n;
            Qs[qh + qq][o] = pacc[qq] + xin[mrow * DM + o];
        }
    }
    __syncthreads();
    const int wv_ = t >> 6, ll = t & 63;
    for (int rq = wv_; rq < 12; rq += 4) {
        float v0 = Qs[rq][ll], v1 = Qs[rq][ll + 64];
        float s = v0 + v1, ss = v0 * v0 + v1 * v1;
        #pragma unroll
        for (int msk = 1; msk < 64; msk <<= 1) {
            s += __shfl_xor(s, msk, 64);
            ss += __shfl_xor(ss, msk, 64);
        }
        float mu = s * (1.0f / 128.0f);
        float var = ss * (1.0f / 128.0f) - mu * mu;
        float rs = rsqrtf(var + 1e-5f);
        size_t mrow = (size_t)(b * NP + rq) * NN_ + n;
        out[mrow * DM + ll]      = (v0 - mu) * rs * gamma[ll] + beta[ll];
        out[mrow * DM + ll + 64] = (v1 - mu) * rs * gamma[ll + 64] + beta[ll + 64];
    }
}

// ---------------- launcher ----------------
extern "C" void kernel_launch(void* const* d_in, const int* in_sizes, int n_in,
                              void* d_out, int out_size, void* d_ws, size_t ws_size,
                              hipStream_t stream) {
    const float* xin   = (const float*)d_in[0];
    const float* Kenc  = (const float*)d_in[1];
    const float* Venc  = (const float*)d_in[2];
    const float* ct    = (const float*)d_in[3];
    const float* W1    = (const float*)d_in[4];
    const float* b1    = (const float*)d_in[5];
    const float* W2    = (const float*)d_in[6];
    const float* b2    = (const float*)d_in[7];
    const float* Wout  = (const float*)d_in[8];
    const float* gamma = (const float*)d_in[9];
    const float* beta  = (const float*)d_in[10];
    float* out = (float*)d_out;

    char* ws = (char*)d_ws;
    unsigned short* W2b = (unsigned short*)(ws);                  //  8,388,608 B
    float* xT  = (float*)(ws + 8388608);                          //  5,111,808 B (128 x 9984)
    float* hb  = (float*)(ws + 13500416);                         // 10,223,616 B (9984 x 256)
    float* Qb  = (float*)(ws + 23724032);                         //  5,111,808 B
    float* Qp  = (float*)(ws + 28835840);                         // 40,894,464 B (8 x 9984 x 128)

    hipLaunchKernelGGL(k_prep, dim3(3374), dim3(256), 0, stream,
                       W2, W2b, xin, xT, ct, W1, b1, b2, hb, Qb);
    hipLaunchKernelGGL(k_gemm, dim3(504), dim3(256), 0, stream, W2b, hb, xT, Qp);
    hipLaunchKernelGGL(k_attn, dim3(828), dim3(256), 0, stream, Qp, Qb, Kenc, Venc,
                       xin, Wout, gamma, beta, out);
}